// Round 8
// baseline (923.323 us; speedup 1.0000x reference)
//
#include <hip/hip_runtime.h>
#include <math.h>

// Multi-query attention, MI355X gfx950.
// b=8, n=s=1024, d=k=v=256, h=8.
// Pre-softmax: bf16 hi/lo 3-pass MFMA (fp32-accurate logits, proven absmax 16).
// Post-softmax: f16 16x16x16 MFMA (lane-local P pack, no shuffles).
// k_attn: 16-s blocks, K hi/lo + V(f16) double-buffered in LDS (48 KB ->
// 2 WGs/CU), flash online softmax, 1 vmcnt(0)+barrier per block.

typedef short bf16x8 __attribute__((ext_vector_type(8)));
typedef __fp16 f16x4 __attribute__((ext_vector_type(4)));
typedef float f32x4  __attribute__((ext_vector_type(4)));

#define MFMA(a, b, c)   __builtin_amdgcn_mfma_f32_16x16x32_bf16((a), (b), (c), 0, 0, 0)
#define MFMA16(a, b, c) __builtin_amdgcn_mfma_f32_16x16x16f16((a), (b), (c), 0, 0, 0)

typedef __attribute__((address_space(3))) unsigned int lds_u32_t;
typedef __attribute__((address_space(1))) const unsigned int glb_u32_t;

__device__ __forceinline__ unsigned short f32_bf16(float f) {
  unsigned u = __float_as_uint(f);
  u += 0x7FFFu + ((u >> 16) & 1u);   // RNE
  return (unsigned short)(u >> 16);
}
__device__ __forceinline__ float bf16_f32(unsigned short h) {
  return __uint_as_float(((unsigned)h) << 16);
}

// ---------------------------------------------------------------------------
// Prep: split x,m,qp,kp into bf16 hi/lo; output_proj -> bf16; vp -> vp^T bf16.
__global__ void k_prep(const float* __restrict__ x, const float* __restrict__ m,
                       const float* __restrict__ op, const float* __restrict__ qp,
                       const float* __restrict__ kp, const float* __restrict__ vp,
                       unsigned short* __restrict__ xh, unsigned short* __restrict__ xl,
                       unsigned short* __restrict__ mh, unsigned short* __restrict__ ml,
                       unsigned short* __restrict__ opb,
                       unsigned short* __restrict__ qph, unsigned short* __restrict__ qpl,
                       unsigned short* __restrict__ kph, unsigned short* __restrict__ kpl,
                       unsigned short* __restrict__ vpt) {
  const int tid = blockIdx.x * blockDim.x + threadIdx.x;
  const int stride = gridDim.x * blockDim.x;
  for (int i = tid; i < 2097152; i += stride) {
    float v = x[i];
    unsigned short h = f32_bf16(v);
    xh[i] = h; xl[i] = f32_bf16(v - bf16_f32(h));
    float w = m[i];
    unsigned short h2 = f32_bf16(w);
    mh[i] = h2; ml[i] = f32_bf16(w - bf16_f32(h2));
  }
  for (int i = tid; i < 524288; i += stride) {
    opb[i] = f32_bf16(op[i]);
    float q = qp[i];
    unsigned short h = f32_bf16(q);
    qph[i] = h; qpl[i] = f32_bf16(q - bf16_f32(h));
  }
  for (int i = tid; i < 65536; i += stride) {
    float k = kp[i];
    unsigned short h = f32_bf16(k);
    kph[i] = h; kpl[i] = f32_bf16(k - bf16_f32(h));
    const int vc = i >> 8, d = i & 255;
    vpt[i] = f32_bf16(vp[d * 256 + vc]);   // vpt[vc][d]
  }
}

// ---------------------------------------------------------------------------
// W[h][j][i] = sum_k Qp[h,i,k]*Kp[j,k]  (3-pass split MFMA, stored hi/lo).
__global__ __launch_bounds__(256) void k_w(
    const unsigned short* __restrict__ qph, const unsigned short* __restrict__ qpl,
    const unsigned short* __restrict__ kph, const unsigned short* __restrict__ kpl,
    unsigned short* __restrict__ wh, unsigned short* __restrict__ wl) {
  const int jt = blockIdx.x & 7;      // 64 WGs = 8h x 8jt
  const int h  = blockIdx.x >> 3;
  const int wave = threadIdx.x >> 6;
  const int lane = threadIdx.x & 63;
  const int lr = lane & 15, lg = lane >> 4;

  f32x4 acc[2][4];
  const f32x4 z = {0.f, 0.f, 0.f, 0.f};
#pragma unroll
  for (int mi = 0; mi < 2; ++mi)
#pragma unroll
    for (int nt = 0; nt < 4; ++nt) acc[mi][nt] = z;

  for (int ks = 0; ks < 8; ++ks) {
    bf16x8 ah[2], al[2], bh[4], bl[4];
#pragma unroll
    for (int mi = 0; mi < 2; ++mi) {
      const size_t aoff = ((size_t)(jt * 32 + mi * 16 + lr)) * 256 + ks * 32 + lg * 8;
      ah[mi] = *(const bf16x8*)(kph + aoff);
      al[mi] = *(const bf16x8*)(kpl + aoff);
    }
#pragma unroll
    for (int nt = 0; nt < 4; ++nt) {
      const size_t boff = ((size_t)(h * 256 + wave * 64 + nt * 16 + lr)) * 256 + ks * 32 + lg * 8;
      bh[nt] = *(const bf16x8*)(qph + boff);
      bl[nt] = *(const bf16x8*)(qpl + boff);
    }
#pragma unroll
    for (int nt = 0; nt < 4; ++nt)
#pragma unroll
      for (int mi = 0; mi < 2; ++mi) {
        acc[mi][nt] = MFMA(ah[mi], bh[nt], acc[mi][nt]);
        acc[mi][nt] = MFMA(ah[mi], bl[nt], acc[mi][nt]);
        acc[mi][nt] = MFMA(al[mi], bh[nt], acc[mi][nt]);
      }
  }
#pragma unroll
  for (int mi = 0; mi < 2; ++mi)
#pragma unroll
    for (int nt = 0; nt < 4; ++nt)
#pragma unroll
      for (int r = 0; r < 4; ++r) {
        const int j = jt * 32 + mi * 16 + lg * 4 + r;
        const int i = wave * 64 + nt * 16 + lr;
        const float v = acc[mi][nt][r];
        const size_t idx = ((size_t)(h * 256 + j)) * 256 + i;
        const unsigned short hi = f32_bf16(v);
        wh[idx] = hi;
        wl[idx] = f32_bf16(v - bf16_f32(hi));
      }
}

// ---------------------------------------------------------------------------
// vt[b][vc][s] = sum_d m[b,s,d]*vp[d,vc]  (1-pass bf16 MFMA, stored f16)
__global__ __launch_bounds__(256) void k_v(
    const unsigned short* __restrict__ vpt, const unsigned short* __restrict__ mh,
    __fp16* __restrict__ vt) {
  const int sc  = blockIdx.x & 3;     // 256 WGs = 8b x 8vct x 4sc
  const int vct = (blockIdx.x >> 2) & 7;
  const int b   = blockIdx.x >> 5;
  const int wave = threadIdx.x >> 6;
  const int lane = threadIdx.x & 63;
  const int lr = lane & 15, lg = lane >> 4;

  f32x4 acc[2][4];
  const f32x4 z = {0.f, 0.f, 0.f, 0.f};
#pragma unroll
  for (int mi = 0; mi < 2; ++mi)
#pragma unroll
    for (int nt = 0; nt < 4; ++nt) acc[mi][nt] = z;

  for (int ks = 0; ks < 8; ++ks) {
    bf16x8 av[2], bv[4];
#pragma unroll
    for (int mi = 0; mi < 2; ++mi)
      av[mi] = *(const bf16x8*)(vpt + ((size_t)(vct * 32 + mi * 16 + lr)) * 256 + ks * 32 + lg * 8);
#pragma unroll
    for (int nt = 0; nt < 4; ++nt)
      bv[nt] = *(const bf16x8*)(mh + ((size_t)(b * 1024 + sc * 256 + wave * 64 + nt * 16 + lr)) * 256 + ks * 32 + lg * 8);
#pragma unroll
    for (int nt = 0; nt < 4; ++nt)
#pragma unroll
      for (int mi = 0; mi < 2; ++mi)
        acc[mi][nt] = MFMA(av[mi], bv[nt], acc[mi][nt]);
  }
#pragma unroll
  for (int mi = 0; mi < 2; ++mi)
#pragma unroll
    for (int nt = 0; nt < 4; ++nt)
#pragma unroll
      for (int r = 0; r < 4; ++r) {
        const int vc = vct * 32 + mi * 16 + lg * 4 + r;
        const int s  = sc * 256 + wave * 64 + nt * 16 + lr;
        vt[((size_t)(b * 256 + vc)) * 1024 + s] = (__fp16)acc[mi][nt][r];
      }
}

// ---------------------------------------------------------------------------
// t[b][h][n][d'] = (x[b,n,:] @ W[h]) / 16, stored bf16 hi/lo (3-pass split MFMA)
__global__ __launch_bounds__(256) void k_t(
    const unsigned short* __restrict__ xh, const unsigned short* __restrict__ xl,
    const unsigned short* __restrict__ wh, const unsigned short* __restrict__ wl,
    unsigned short* __restrict__ th, unsigned short* __restrict__ tl) {
  const int wg = blockIdx.x;        // 2048 = b*h*(1024/32)
  const int mt = wg & 31;
  const int h  = (wg >> 5) & 7;
  const int b  = wg >> 8;
  const int wave = threadIdx.x >> 6;
  const int lane = threadIdx.x & 63;
  const int lr = lane & 15, lg = lane >> 4;

  f32x4 acc[2][4];
  const f32x4 z = {0.f, 0.f, 0.f, 0.f};
#pragma unroll
  for (int mi = 0; mi < 2; ++mi)
#pragma unroll
    for (int nt = 0; nt < 4; ++nt) acc[mi][nt] = z;

  for (int ks = 0; ks < 8; ++ks) {
    bf16x8 ahv[2], alv[2], bh4[4], bl4[4];
#pragma unroll
    for (int mi = 0; mi < 2; ++mi) {
      const size_t aoff = ((size_t)(b * 1024 + mt * 32 + mi * 16 + lr)) * 256 + ks * 32 + lg * 8;
      ahv[mi] = *(const bf16x8*)(xh + aoff);
      alv[mi] = *(const bf16x8*)(xl + aoff);
    }
#pragma unroll
    for (int nt = 0; nt < 4; ++nt) {
      const int dc = wave * 64 + nt * 16 + lr;
      const size_t boff = ((size_t)(h * 256 + dc)) * 256 + ks * 32 + lg * 8;
      bh4[nt] = *(const bf16x8*)(wh + boff);
      bl4[nt] = *(const bf16x8*)(wl + boff);
    }
#pragma unroll
    for (int nt = 0; nt < 4; ++nt)
#pragma unroll
      for (int mi = 0; mi < 2; ++mi) {
        acc[mi][nt] = MFMA(ahv[mi], bh4[nt], acc[mi][nt]);
        acc[mi][nt] = MFMA(ahv[mi], bl4[nt], acc[mi][nt]);
        acc[mi][nt] = MFMA(alv[mi], bh4[nt], acc[mi][nt]);
      }
  }
#pragma unroll
  for (int mi = 0; mi < 2; ++mi)
#pragma unroll
    for (int nt = 0; nt < 4; ++nt)
#pragma unroll
      for (int r = 0; r < 4; ++r) {
        const int row = mt * 32 + mi * 16 + lg * 4 + r;
        const int dc  = wave * 64 + nt * 16 + lr;
        const float v = acc[mi][nt][r] * 0.0625f;   // fold 1/sqrt(256)
        const size_t idx = ((size_t)((b * 8 + h) * 1024 + row)) * 256 + dc;
        const unsigned short hi = f32_bf16(v);
        th[idx] = hi;
        tl[idx] = f32_bf16(v - bf16_f32(hi));
      }
}

// ---------------------------------------------------------------------------
// Flash attention per (b, h, 128-q-row tile). 8 waves x 16 q-rows, 512 WGs.
// 16-s blocks (64 iters). K hi/lo + V(f16) double-buffered, 48 KB LDS ->
// 2 WGs/CU. PV uses 16x16x16 f16 MFMA with LANE-LOCAL P pack (no shuffles).
__global__ __launch_bounds__(512, 4) void k_attn(
    const unsigned short* __restrict__ th, const unsigned short* __restrict__ tl,
    const unsigned short* __restrict__ mh, const unsigned short* __restrict__ ml,
    const __fp16* __restrict__ vt, unsigned short* __restrict__ ob) {
  __shared__ __align__(16) unsigned short KH[2][4096];   // 16 s x 256 d (swizzled)
  __shared__ __align__(16) unsigned short KL[2][4096];
  __shared__ __align__(16) __fp16         VB[2][4096];   // 256 vc x 16 s (linear)

  const int wg0 = blockIdx.x;
  const int wg = (wg0 & 7) * 64 + (wg0 >> 3);   // XCD swizzle: b = XCD id
  const int qt = wg & 7;
  const int h  = (wg >> 3) & 7;
  const int b  = wg >> 6;
  const int wv = threadIdx.x >> 6;              // 0..7
  const int lane = threadIdx.x & 63;
  const int lr = lane & 15, lg = lane >> 4;
  const int start = ((qt << 3) + h) & 63;       // stagger block order per WG

  // Hoist t (B-operand for swapped QK^T): q = lr.
  const size_t trow = ((size_t)((b * 8 + h) * 1024 + qt * 128 + wv * 16 + lr)) * 256;
  bf16x8 Th[8], Tl[8];
#pragma unroll
  for (int d = 0; d < 8; ++d) {
    Th[d] = *(const bf16x8*)(th + trow + d * 32 + lg * 8);
    Tl[d] = *(const bf16x8*)(tl + trow + d * 32 + lg * 8);
  }

  const size_t mbase = (size_t)b * 1024 * 256;
  const size_t vbase = (size_t)b * 256 * 1024;

  // Stage K-block (16s x 256d, hi+lo). Linear LDS dest; source pre-swizzled
  // so LDS 16B-unit u holds global unit u ^ (s&7). 1 load/wave per array.
  auto stageK = [&](int lblk, int bi) {
    const int U = wv * 64 + lane;               // 0..511
    const int s_loc = U >> 5, u_phys = U & 31;
    const int u_log = u_phys ^ (s_loc & 7);
    const int pb = (lblk + start) & 63;
    const size_t soff = mbase + ((size_t)(pb * 16 + s_loc)) * 256 + u_log * 8;
    const int dsts = U * 8;                     // shorts, wave-uniform base
    __builtin_amdgcn_global_load_lds((glb_u32_t*)(mh + soff), (lds_u32_t*)&KH[bi][dsts], 16, 0, 0);
    __builtin_amdgcn_global_load_lds((glb_u32_t*)(ml + soff), (lds_u32_t*)&KL[bi][dsts], 16, 0, 0);
  };
  // Stage V-block (256vc x 16s f16), rows 32B, linear (b64 reads hit bank floor).
  auto stageV = [&](int lblk, int bi) {
    const int U = wv * 64 + lane;               // 0..511
    const int vc = U >> 1, u = U & 1;
    const int pb = (lblk + start) & 63;
    const size_t soff = vbase + (size_t)vc * 1024 + pb * 16 + u * 8;
    __builtin_amdgcn_global_load_lds((glb_u32_t*)(vt + soff), (lds_u32_t*)&VB[bi][U * 8], 16, 0, 0);
  };

  f32x4 Oacc[16];
  const f32x4 z = {0.f, 0.f, 0.f, 0.f};
#pragma unroll
  for (int i = 0; i < 16; ++i) Oacc[i] = z;
  float mrun = -1e30f, lrun = 0.0f;
  const float LOG2E = 1.44269504f;

  // ---- prologue: stage blocks 0 and 1 (3 loads per wave per stage)
  stageK(0, 0); stageV(0, 0);
  stageK(1, 1); stageV(1, 1);
  asm volatile("s_waitcnt vmcnt(3)" ::: "memory");   // stage(0) landed
  __builtin_amdgcn_s_barrier();

#pragma unroll 1
  for (int blk = 0; blk < 64; ++blk) {
    const int p = blk & 1;

    // ---- QK^T(blk): S^T tile (s = lg*4+r, q = lr), 3 independent chains
    f32x4 Sa = z, Sb = z, Sc = z;
#pragma unroll
    for (int d = 0; d < 8; ++d) {
      const int u0 = ((d * 4 + lg) ^ (lr & 7)) * 8;
      const bf16x8 a_h = *(const bf16x8*)&KH[p][lr * 256 + u0];
      const bf16x8 a_l = *(const bf16x8*)&KL[p][lr * 256 + u0];
      Sa = MFMA(a_h, Th[d], Sa);
      Sb = MFMA(a_h, Tl[d], Sb);
      Sc = MFMA(a_l, Th[d], Sc);
    }
    const f32x4 S = (Sa + Sb) + Sc;

    // ---- online softmax (true logits; q = lr domain)
    float bm = fmaxf(fmaxf(S[0], S[1]), fmaxf(S[2], S[3]));
    bm = fmaxf(bm, __shfl_xor(bm, 16));
    bm = fmaxf(bm, __shfl_xor(bm, 32));
    if (!__all(bm - mrun <= 8.0f)) {            // defer-max: THR = 8 nats
      const float mnew = fmaxf(mrun, bm);
      const float sc = exp2f((mrun - mnew) * LOG2E);
      const float s0 = __shfl(sc, lg * 4 + 0);
      const float s1 = __shfl(sc, lg * 4 + 1);
      const float s2 = __shfl(sc, lg * 4 + 2);
      const float s3 = __shfl(sc, lg * 4 + 3);
#pragma unroll
      for (int nt = 0; nt < 16; ++nt) {
        Oacc[nt][0] *= s0; Oacc[nt][1] *= s1; Oacc[nt][2] *= s2; Oacc[nt][3] *= s3;
      }
      lrun *= sc;
      mrun = mnew;
    }
    float pr[4];
#pragma unroll
    for (int r = 0; r < 4; ++r) pr[r] = exp2f((S[r] - mrun) * LOG2E);
    float rs = (pr[0] + pr[1]) + (pr[2] + pr[3]);
    rs += __shfl_xor(rs, 16);
    rs += __shfl_xor(rs, 32);
    lrun += rs;

    // ---- pack P: lane-local! A-frag[m=lr][k=lg*4+j] == this lane's pr[j]
    const auto c01 = __builtin_amdgcn_cvt_pkrtz(pr[0], pr[1]);   // __fp16 x2
    const auto c23 = __builtin_amdgcn_cvt_pkrtz(pr[2], pr[3]);
    f16x4 pa;
    pa[0] = c01[0]; pa[1] = c01[1]; pa[2] = c23[0]; pa[3] = c23[1];

    // ---- PV(blk): B[k=s][n=vc] from VB rows (b64, bank-floor)
#pragma unroll
    for (int nt = 0; nt < 16; ++nt) {
      const f16x4 bv = *(const f16x4*)&VB[p][(nt * 16 + lr) * 16 + lg * 4];
      Oacc[nt] = MFMA16(pa, bv, Oacc[nt]);
    }

    // ---- pipeline: own stages drained; collective barrier => all waves'
    // stage(blk+1) landed and all reads of buffers p complete.
    if (blk < 63) {
      asm volatile("s_waitcnt vmcnt(0)" ::: "memory");
      __builtin_amdgcn_s_barrier();
      if (blk < 62) { stageK(blk + 2, p); stageV(blk + 2, p); }
    }
  }

  // ---- epilogue
  const float inv = 1.0f / lrun;
  const float i0 = __shfl(inv, lg * 4 + 0);
  const float i1 = __shfl(inv, lg * 4 + 1);
  const float i2 = __shfl(inv, lg * 4 + 2);
  const float i3 = __shfl(inv, lg * 4 + 3);
  const int qg = qt * 128 + wv * 16 + lg * 4;
  const size_t obase = ((size_t)(b * 1024 + qg) * 8 + h) * 256 + lr;
#pragma unroll
  for (int nt = 0; nt < 16; ++nt) {
    ob[obase + 0 * 2048 + nt * 16] = f32_bf16(Oacc[nt][0] * i0);
    ob[obase + 1 * 2048 + nt * 16] = f32_bf16(Oacc[nt][1] * i1);
    ob[obase + 2 * 2048 + nt * 16] = f32_bf16(Oacc[nt][2] * i2);
    ob[obase + 3 * 2048 + nt * 16] = f32_bf16(Oacc[nt][3] * i3);
  }
}

// ---------------------------------------------------------------------------
// out[bn][d] = o[bn][hv] @ OpB[d][hv]^T  (M=8192, K=2048, N=256)
__global__ __launch_bounds__(256) void k_out(
    const unsigned short* __restrict__ ob, const unsigned short* __restrict__ opb,
    float* __restrict__ out) {
  const int wg = blockIdx.x;        // 256 = 8192/32
  const int wave = threadIdx.x >> 6;
  const int lane = threadIdx.x & 63;
  const int lr = lane & 15, lg = lane >> 4;

  f32x4 acc[2][4];
  const f32x4 z = {0.f, 0.f, 0.f, 0.f};
#pragma unroll
  for (int mi = 0; mi < 2; ++mi)
#pragma unroll
    for (int nt = 0; nt < 4; ++nt) acc[mi][nt] = z;

  for (int ks = 0; ks < 64; ++ks) {
    bf16x8 av[2], bv[4];
#pragma unroll
    for (int mi = 0; mi < 2; ++mi) {
      const size_t aoff = ((size_t)(wg * 32 + mi * 16 + lr)) * 2048 + ks * 32 + lg * 8;
      av[mi] = *(const bf16x8*)(ob + aoff);
    }
#pragma unroll
    for (int nt = 0; nt < 4; ++nt) {
      const int dc = wave * 64 + nt * 16 + lr;
      bv[nt] = *(const bf16x8*)(opb + ((size_t)dc) * 2048 + ks * 32 + lg * 8);
    }
#pragma unroll
    for (int nt = 0; nt < 4; ++nt)
#pragma unroll
      for (int mi = 0; mi < 2; ++mi)
        acc[mi][nt] = MFMA(av[mi], bv[nt], acc[mi][nt]);
  }
#pragma unroll
  for (int mi = 0; mi < 2; ++mi)
#pragma unroll
    for (int nt = 0; nt < 4; ++nt)
#pragma unroll
      for (int r = 0; r < 4; ++r) {
        const int row = wg * 32 + mi * 16 + lg * 4 + r;
        const int dc  = wave * 64 + nt * 16 + lr;
        out[(size_t)row * 256 + dc] = acc[mi][nt][r];
      }
}

// ---------------------------------------------------------------------------
extern "C" void kernel_launch(void* const* d_in, const int* in_sizes, int n_in,
                              void* d_out, int out_size, void* d_ws, size_t ws_size,
                              hipStream_t stream) {
  const float* x  = (const float*)d_in[0];
  const float* m  = (const float*)d_in[1];
  const float* qp = (const float*)d_in[2];
  const float* kp = (const float*)d_in[3];
  const float* vp = (const float*)d_in[4];
  const float* op = (const float*)d_in[5];
  float* out = (float*)d_out;

  unsigned short* xh  = (unsigned short*)d_ws;            // [8][1024][256]
  unsigned short* xl  = xh  + 2097152;
  unsigned short* mh  = xl  + 2097152;                    // [8][1024][256]
  unsigned short* ml  = mh  + 2097152;
  unsigned short* wh  = ml  + 2097152;                    // [8][256][256] (j major)
  unsigned short* wl  = wh  + 524288;
  unsigned short* opb = wl  + 524288;                     // [256][2048]
  __fp16*         vt  = (__fp16*)(opb + 524288);          // [8][256][1024] f16
  unsigned short* th  = (unsigned short*)(vt + 2097152);  // [8][8][1024][256]
  unsigned short* tl  = th  + 16777216;
  unsigned short* ob  = tl  + 16777216;                   // [8][1024][8][256]
  unsigned short* qph = ob  + 16777216;                   // [8][256][256]
  unsigned short* qpl = qph + 524288;
  unsigned short* kph = qpl + 524288;                     // [256][256]
  unsigned short* kpl = kph + 65536;
  unsigned short* vpt = kpl + 65536;                      // [256][256]

  k_prep<<<2048, 256, 0, stream>>>(x, m, op, qp, kp, vp, xh, xl, mh, ml, opb,
                                   qph, qpl, kph, kpl, vpt);
  k_w   <<<64,   256, 0, stream>>>(qph, qpl, kph, kpl, wh, wl);
  k_v   <<<256,  256, 0, stream>>>(vpt, mh, vt);
  k_t   <<<2048, 256, 0, stream>>>(xh, xl, wh, wl, th, tl);
  k_attn<<<512,  512, 0, stream>>>(th, tl, mh, ml, vt, ob);
  k_out <<<256,  256, 0, stream>>>(ob, opb, out);
}

// Round 9
// 525.900 us; speedup vs baseline: 1.7557x; 1.7557x over previous
//
#include <hip/hip_runtime.h>
#include <math.h>

// Multi-query attention, MI355X gfx950.
// b=8, n=s=1024, d=k=v=256, h=8.
// Pre-softmax: bf16 hi/lo 3-pass MFMA (fp32-accurate logits, proven absmax 16).
// Post-softmax: f16 16x16x16 MFMA (lane-local P pack, no shuffles).
// k_attn: 4-wave WGs (64 q), 16-s blocks, K hi/lo + V(f16) double-buffered in
// LDS (48 KB -> 3 WGs/CU), flash online softmax, 1 vmcnt(0)+barrier per block.

typedef short bf16x8 __attribute__((ext_vector_type(8)));
typedef __fp16 f16x4 __attribute__((ext_vector_type(4)));
typedef float f32x4  __attribute__((ext_vector_type(4)));

#define MFMA(a, b, c)   __builtin_amdgcn_mfma_f32_16x16x32_bf16((a), (b), (c), 0, 0, 0)
#define MFMA16(a, b, c) __builtin_amdgcn_mfma_f32_16x16x16f16((a), (b), (c), 0, 0, 0)

typedef __attribute__((address_space(3))) unsigned int lds_u32_t;
typedef __attribute__((address_space(1))) const unsigned int glb_u32_t;

__device__ __forceinline__ unsigned short f32_bf16(float f) {
  unsigned u = __float_as_uint(f);
  u += 0x7FFFu + ((u >> 16) & 1u);   // RNE
  return (unsigned short)(u >> 16);
}
__device__ __forceinline__ float bf16_f32(unsigned short h) {
  return __uint_as_float(((unsigned)h) << 16);
}

// ---------------------------------------------------------------------------
// Prep: split x,m,qp,kp into bf16 hi/lo; output_proj -> bf16; vp -> vp^T bf16.
__global__ void k_prep(const float* __restrict__ x, const float* __restrict__ m,
                       const float* __restrict__ op, const float* __restrict__ qp,
                       const float* __restrict__ kp, const float* __restrict__ vp,
                       unsigned short* __restrict__ xh, unsigned short* __restrict__ xl,
                       unsigned short* __restrict__ mh, unsigned short* __restrict__ ml,
                       unsigned short* __restrict__ opb,
                       unsigned short* __restrict__ qph, unsigned short* __restrict__ qpl,
                       unsigned short* __restrict__ kph, unsigned short* __restrict__ kpl,
                       unsigned short* __restrict__ vpt) {
  const int tid = blockIdx.x * blockDim.x + threadIdx.x;
  const int stride = gridDim.x * blockDim.x;
  for (int i = tid; i < 2097152; i += stride) {
    float v = x[i];
    unsigned short h = f32_bf16(v);
    xh[i] = h; xl[i] = f32_bf16(v - bf16_f32(h));
    float w = m[i];
    unsigned short h2 = f32_bf16(w);
    mh[i] = h2; ml[i] = f32_bf16(w - bf16_f32(h2));
  }
  for (int i = tid; i < 524288; i += stride) {
    opb[i] = f32_bf16(op[i]);
    float q = qp[i];
    unsigned short h = f32_bf16(q);
    qph[i] = h; qpl[i] = f32_bf16(q - bf16_f32(h));
  }
  for (int i = tid; i < 65536; i += stride) {
    float k = kp[i];
    unsigned short h = f32_bf16(k);
    kph[i] = h; kpl[i] = f32_bf16(k - bf16_f32(h));
    const int vc = i >> 8, d = i & 255;
    vpt[i] = f32_bf16(vp[d * 256 + vc]);   // vpt[vc][d]
  }
}

// ---------------------------------------------------------------------------
// W[h][j][i] = sum_k Qp[h,i,k]*Kp[j,k]  (3-pass split MFMA, stored hi/lo).
__global__ __launch_bounds__(256) void k_w(
    const unsigned short* __restrict__ qph, const unsigned short* __restrict__ qpl,
    const unsigned short* __restrict__ kph, const unsigned short* __restrict__ kpl,
    unsigned short* __restrict__ wh, unsigned short* __restrict__ wl) {
  const int jt = blockIdx.x & 7;      // 64 WGs = 8h x 8jt
  const int h  = blockIdx.x >> 3;
  const int wave = threadIdx.x >> 6;
  const int lane = threadIdx.x & 63;
  const int lr = lane & 15, lg = lane >> 4;

  f32x4 acc[2][4];
  const f32x4 z = {0.f, 0.f, 0.f, 0.f};
#pragma unroll
  for (int mi = 0; mi < 2; ++mi)
#pragma unroll
    for (int nt = 0; nt < 4; ++nt) acc[mi][nt] = z;

  for (int ks = 0; ks < 8; ++ks) {
    bf16x8 ah[2], al[2], bh[4], bl[4];
#pragma unroll
    for (int mi = 0; mi < 2; ++mi) {
      const size_t aoff = ((size_t)(jt * 32 + mi * 16 + lr)) * 256 + ks * 32 + lg * 8;
      ah[mi] = *(const bf16x8*)(kph + aoff);
      al[mi] = *(const bf16x8*)(kpl + aoff);
    }
#pragma unroll
    for (int nt = 0; nt < 4; ++nt) {
      const size_t boff = ((size_t)(h * 256 + wave * 64 + nt * 16 + lr)) * 256 + ks * 32 + lg * 8;
      bh[nt] = *(const bf16x8*)(qph + boff);
      bl[nt] = *(const bf16x8*)(qpl + boff);
    }
#pragma unroll
    for (int nt = 0; nt < 4; ++nt)
#pragma unroll
      for (int mi = 0; mi < 2; ++mi) {
        acc[mi][nt] = MFMA(ah[mi], bh[nt], acc[mi][nt]);
        acc[mi][nt] = MFMA(ah[mi], bl[nt], acc[mi][nt]);
        acc[mi][nt] = MFMA(al[mi], bh[nt], acc[mi][nt]);
      }
  }
#pragma unroll
  for (int mi = 0; mi < 2; ++mi)
#pragma unroll
    for (int nt = 0; nt < 4; ++nt)
#pragma unroll
      for (int r = 0; r < 4; ++r) {
        const int j = jt * 32 + mi * 16 + lg * 4 + r;
        const int i = wave * 64 + nt * 16 + lr;
        const float v = acc[mi][nt][r];
        const size_t idx = ((size_t)(h * 256 + j)) * 256 + i;
        const unsigned short hi = f32_bf16(v);
        wh[idx] = hi;
        wl[idx] = f32_bf16(v - bf16_f32(hi));
      }
}

// ---------------------------------------------------------------------------
// vt[b][vc][s] = sum_d m[b,s,d]*vp[d,vc]  (1-pass bf16 MFMA, stored f16)
__global__ __launch_bounds__(256) void k_v(
    const unsigned short* __restrict__ vpt, const unsigned short* __restrict__ mh,
    __fp16* __restrict__ vt) {
  const int sc  = blockIdx.x & 3;     // 256 WGs = 8b x 8vct x 4sc
  const int vct = (blockIdx.x >> 2) & 7;
  const int b   = blockIdx.x >> 5;
  const int wave = threadIdx.x >> 6;
  const int lane = threadIdx.x & 63;
  const int lr = lane & 15, lg = lane >> 4;

  f32x4 acc[2][4];
  const f32x4 z = {0.f, 0.f, 0.f, 0.f};
#pragma unroll
  for (int mi = 0; mi < 2; ++mi)
#pragma unroll
    for (int nt = 0; nt < 4; ++nt) acc[mi][nt] = z;

  for (int ks = 0; ks < 8; ++ks) {
    bf16x8 av[2], bv[4];
#pragma unroll
    for (int mi = 0; mi < 2; ++mi)
      av[mi] = *(const bf16x8*)(vpt + ((size_t)(vct * 32 + mi * 16 + lr)) * 256 + ks * 32 + lg * 8);
#pragma unroll
    for (int nt = 0; nt < 4; ++nt)
      bv[nt] = *(const bf16x8*)(mh + ((size_t)(b * 1024 + sc * 256 + wave * 64 + nt * 16 + lr)) * 256 + ks * 32 + lg * 8);
#pragma unroll
    for (int nt = 0; nt < 4; ++nt)
#pragma unroll
      for (int mi = 0; mi < 2; ++mi)
        acc[mi][nt] = MFMA(av[mi], bv[nt], acc[mi][nt]);
  }
#pragma unroll
  for (int mi = 0; mi < 2; ++mi)
#pragma unroll
    for (int nt = 0; nt < 4; ++nt)
#pragma unroll
      for (int r = 0; r < 4; ++r) {
        const int vc = vct * 32 + mi * 16 + lg * 4 + r;
        const int s  = sc * 256 + wave * 64 + nt * 16 + lr;
        vt[((size_t)(b * 256 + vc)) * 1024 + s] = (__fp16)acc[mi][nt][r];
      }
}

// ---------------------------------------------------------------------------
// t[b][h][n][d'] = (x[b,n,:] @ W[h]) / 16, stored bf16 hi/lo (3-pass split MFMA)
__global__ __launch_bounds__(256) void k_t(
    const unsigned short* __restrict__ xh, const unsigned short* __restrict__ xl,
    const unsigned short* __restrict__ wh, const unsigned short* __restrict__ wl,
    unsigned short* __restrict__ th, unsigned short* __restrict__ tl) {
  const int wg = blockIdx.x;        // 2048 = b*h*(1024/32)
  const int mt = wg & 31;
  const int h  = (wg >> 5) & 7;
  const int b  = wg >> 8;
  const int wave = threadIdx.x >> 6;
  const int lane = threadIdx.x & 63;
  const int lr = lane & 15, lg = lane >> 4;

  f32x4 acc[2][4];
  const f32x4 z = {0.f, 0.f, 0.f, 0.f};
#pragma unroll
  for (int mi = 0; mi < 2; ++mi)
#pragma unroll
    for (int nt = 0; nt < 4; ++nt) acc[mi][nt] = z;

  for (int ks = 0; ks < 8; ++ks) {
    bf16x8 ahv[2], alv[2], bh4[4], bl4[4];
#pragma unroll
    for (int mi = 0; mi < 2; ++mi) {
      const size_t aoff = ((size_t)(b * 1024 + mt * 32 + mi * 16 + lr)) * 256 + ks * 32 + lg * 8;
      ahv[mi] = *(const bf16x8*)(xh + aoff);
      alv[mi] = *(const bf16x8*)(xl + aoff);
    }
#pragma unroll
    for (int nt = 0; nt < 4; ++nt) {
      const int dc = wave * 64 + nt * 16 + lr;
      const size_t boff = ((size_t)(h * 256 + dc)) * 256 + ks * 32 + lg * 8;
      bh4[nt] = *(const bf16x8*)(wh + boff);
      bl4[nt] = *(const bf16x8*)(wl + boff);
    }
#pragma unroll
    for (int nt = 0; nt < 4; ++nt)
#pragma unroll
      for (int mi = 0; mi < 2; ++mi) {
        acc[mi][nt] = MFMA(ahv[mi], bh4[nt], acc[mi][nt]);
        acc[mi][nt] = MFMA(ahv[mi], bl4[nt], acc[mi][nt]);
        acc[mi][nt] = MFMA(alv[mi], bh4[nt], acc[mi][nt]);
      }
  }
#pragma unroll
  for (int mi = 0; mi < 2; ++mi)
#pragma unroll
    for (int nt = 0; nt < 4; ++nt)
#pragma unroll
      for (int r = 0; r < 4; ++r) {
        const int row = mt * 32 + mi * 16 + lg * 4 + r;
        const int dc  = wave * 64 + nt * 16 + lr;
        const float v = acc[mi][nt][r] * 0.0625f;   // fold 1/sqrt(256)
        const size_t idx = ((size_t)((b * 8 + h) * 1024 + row)) * 256 + dc;
        const unsigned short hi = f32_bf16(v);
        th[idx] = hi;
        tl[idx] = f32_bf16(v - bf16_f32(hi));
      }
}

// ---------------------------------------------------------------------------
// Flash attention per (b, h, 64-q-row tile). 4 waves x 16 q-rows, 1024 WGs.
// 16-s blocks (64 iters). K hi/lo + V(f16) double-buffered, 48 KB LDS ->
// 3 WGs/CU. PV uses 16x16x16 f16 MFMA with LANE-LOCAL P pack (no shuffles).
__global__ __launch_bounds__(256, 3) void k_attn(
    const unsigned short* __restrict__ th, const unsigned short* __restrict__ tl,
    const unsigned short* __restrict__ mh, const unsigned short* __restrict__ ml,
    const __fp16* __restrict__ vt, unsigned short* __restrict__ ob) {
  __shared__ __align__(16) unsigned short KH[2][4096];   // 16 s x 256 d (swizzled)
  __shared__ __align__(16) unsigned short KL[2][4096];
  __shared__ __align__(16) __fp16         VB[2][4096];   // 256 vc x 16 s (linear)

  const int wg0 = blockIdx.x;
  const int wg = (wg0 & 7) * 128 + (wg0 >> 3);  // XCD swizzle: b = XCD id
  const int qt = wg & 15;
  const int h  = (wg >> 4) & 7;
  const int b  = wg >> 7;
  const int wv = threadIdx.x >> 6;              // 0..3
  const int lane = threadIdx.x & 63;
  const int lr = lane & 15, lg = lane >> 4;
  const int start = ((qt << 3) + h) & 63;       // stagger block order per WG

  // Hoist t (B-operand for swapped QK^T): q = lr.
  const size_t trow = ((size_t)((b * 8 + h) * 1024 + qt * 64 + wv * 16 + lr)) * 256;
  bf16x8 Th[8], Tl[8];
#pragma unroll
  for (int d = 0; d < 8; ++d) {
    Th[d] = *(const bf16x8*)(th + trow + d * 32 + lg * 8);
    Tl[d] = *(const bf16x8*)(tl + trow + d * 32 + lg * 8);
  }

  const size_t mbase = (size_t)b * 1024 * 256;
  const size_t vbase = (size_t)b * 256 * 1024;

  // Stage K-block (16s x 256d, hi+lo). Linear LDS dest (wave-uniform base);
  // source pre-swizzled so LDS 16B-unit u holds global unit u ^ (s&7).
  auto stageK = [&](int lblk, int bi) {
    const int pb = (lblk + start) & 63;
#pragma unroll
    for (int i = 0; i < 2; ++i) {
      const int U = wv * 128 + i * 64 + lane;
      const int s_loc = U >> 5, u_phys = U & 31;
      const int u_log = u_phys ^ (s_loc & 7);
      const size_t soff = mbase + ((size_t)(pb * 16 + s_loc)) * 256 + u_log * 8;
      const int dsts = (wv * 128 + i * 64) * 8;      // shorts, wave-uniform
      __builtin_amdgcn_global_load_lds((glb_u32_t*)(mh + soff), (lds_u32_t*)&KH[bi][dsts], 16, 0, 0);
      __builtin_amdgcn_global_load_lds((glb_u32_t*)(ml + soff), (lds_u32_t*)&KL[bi][dsts], 16, 0, 0);
    }
  };
  // Stage V-block (256vc x 16s f16), rows 32B, linear.
  auto stageV = [&](int lblk, int bi) {
    const int pb = (lblk + start) & 63;
#pragma unroll
    for (int i = 0; i < 2; ++i) {
      const int U = wv * 128 + i * 64 + lane;
      const int vc = U >> 1, u = U & 1;
      const size_t soff = vbase + (size_t)vc * 1024 + pb * 16 + u * 8;
      const int dsth = (wv * 128 + i * 64) * 8;      // halfs, wave-uniform
      __builtin_amdgcn_global_load_lds((glb_u32_t*)(vt + soff), (lds_u32_t*)&VB[bi][dsth], 16, 0, 0);
    }
  };

  f32x4 Oacc[16];
  const f32x4 z = {0.f, 0.f, 0.f, 0.f};
#pragma unroll
  for (int i = 0; i < 16; ++i) Oacc[i] = z;
  float mrun = -1e30f, lrun = 0.0f;
  const float LOG2E = 1.44269504f;

  // ---- prologue: stage blocks 0 and 1 (6 loads per wave per stage)
  stageK(0, 0); stageV(0, 0);
  stageK(1, 1); stageV(1, 1);
  asm volatile("s_waitcnt vmcnt(6)" ::: "memory");   // stage(0) landed
  __builtin_amdgcn_s_barrier();

#pragma unroll 1
  for (int blk = 0; blk < 64; ++blk) {
    const int p = blk & 1;

    // ---- QK^T(blk): S^T tile (s = lg*4+r, q = lr), 3 independent chains
    f32x4 Sa = z, Sb = z, Sc = z;
#pragma unroll
    for (int d = 0; d < 8; ++d) {
      const int u0 = ((d * 4 + lg) ^ (lr & 7)) * 8;
      const bf16x8 a_h = *(const bf16x8*)&KH[p][lr * 256 + u0];
      const bf16x8 a_l = *(const bf16x8*)&KL[p][lr * 256 + u0];
      Sa = MFMA(a_h, Th[d], Sa);
      Sb = MFMA(a_h, Tl[d], Sb);
      Sc = MFMA(a_l, Th[d], Sc);
    }
    const f32x4 S = (Sa + Sb) + Sc;

    // ---- online softmax (q = lr domain)
    float bm = fmaxf(fmaxf(S[0], S[1]), fmaxf(S[2], S[3]));
    bm = fmaxf(bm, __shfl_xor(bm, 16));
    bm = fmaxf(bm, __shfl_xor(bm, 32));
    if (!__all(bm - mrun <= 8.0f)) {            // defer-max: THR = 8 nats
      const float mnew = fmaxf(mrun, bm);
      const float sc = exp2f((mrun - mnew) * LOG2E);
      const float s0 = __shfl(sc, lg * 4 + 0);
      const float s1 = __shfl(sc, lg * 4 + 1);
      const float s2 = __shfl(sc, lg * 4 + 2);
      const float s3 = __shfl(sc, lg * 4 + 3);
#pragma unroll
      for (int nt = 0; nt < 16; ++nt) {
        Oacc[nt][0] *= s0; Oacc[nt][1] *= s1; Oacc[nt][2] *= s2; Oacc[nt][3] *= s3;
      }
      lrun *= sc;
      mrun = mnew;
    }
    float pr[4];
#pragma unroll
    for (int r = 0; r < 4; ++r) pr[r] = exp2f((S[r] - mrun) * LOG2E);
    float rs = (pr[0] + pr[1]) + (pr[2] + pr[3]);
    rs += __shfl_xor(rs, 16);
    rs += __shfl_xor(rs, 32);
    lrun += rs;

    // ---- pack P: lane-local! A-frag[m=lr][k=lg*4+j] == this lane's pr[j]
    const auto c01 = __builtin_amdgcn_cvt_pkrtz(pr[0], pr[1]);   // __fp16 x2
    const auto c23 = __builtin_amdgcn_cvt_pkrtz(pr[2], pr[3]);
    f16x4 pa;
    pa[0] = c01[0]; pa[1] = c01[1]; pa[2] = c23[0]; pa[3] = c23[1];

    // ---- PV(blk): B[k=s][n=vc] from VB rows (b64)
#pragma unroll
    for (int nt = 0; nt < 16; ++nt) {
      const f16x4 bv = *(const f16x4*)&VB[p][(nt * 16 + lr) * 16 + lg * 4];
      Oacc[nt] = MFMA16(pa, bv, Oacc[nt]);
    }

    // ---- pipeline: own stages drained; collective barrier => all waves'
    // stage(blk+1) landed and all reads of buffers p complete.
    if (blk < 63) {
      asm volatile("s_waitcnt vmcnt(0)" ::: "memory");
      __builtin_amdgcn_s_barrier();
      if (blk < 62) { stageK(blk + 2, p); stageV(blk + 2, p); }
    }
  }

  // ---- epilogue
  const float inv = 1.0f / lrun;
  const float i0 = __shfl(inv, lg * 4 + 0);
  const float i1 = __shfl(inv, lg * 4 + 1);
  const float i2 = __shfl(inv, lg * 4 + 2);
  const float i3 = __shfl(inv, lg * 4 + 3);
  const int qg = qt * 64 + wv * 16 + lg * 4;
  const size_t obase = ((size_t)(b * 1024 + qg) * 8 + h) * 256 + lr;
#pragma unroll
  for (int nt = 0; nt < 16; ++nt) {
    ob[obase + 0 * 2048 + nt * 16] = f32_bf16(Oacc[nt][0] * i0);
    ob[obase + 1 * 2048 + nt * 16] = f32_bf16(Oacc[nt][1] * i1);
    ob[obase + 2 * 2048 + nt * 16] = f32_bf16(Oacc[nt][2] * i2);
    ob[obase + 3 * 2048 + nt * 16] = f32_bf16(Oacc[nt][3] * i3);
  }
}

// ---------------------------------------------------------------------------
// out[bn][d] = o[bn][hv] @ OpB[d][hv]^T  (M=8192, K=2048, N=256)
__global__ __launch_bounds__(256) void k_out(
    const unsigned short* __restrict__ ob, const unsigned short* __restrict__ opb,
    float* __restrict__ out) {
  const int wg = blockIdx.x;        // 256 = 8192/32
  const int wave = threadIdx.x >> 6;
  const int lane = threadIdx.x & 63;
  const int lr = lane & 15, lg = lane >> 4;

  f32x4 acc[2][4];
  const f32x4 z = {0.f, 0.f, 0.f, 0.f};
#pragma unroll
  for (int mi = 0; mi < 2; ++mi)
#pragma unroll
    for (int nt = 0; nt < 4; ++nt) acc[mi][nt] = z;

  for (int ks = 0; ks < 64; ++ks) {
    bf16x8 av[2], bv[4];
#pragma unroll
    for (int mi = 0; mi < 2; ++mi) {
      const size_t aoff = ((size_t)(wg * 32 + mi * 16 + lr)) * 2048 + ks * 32 + lg * 8;
      av[mi] = *(const bf16x8*)(ob + aoff);
    }
#pragma unroll
    for (int nt = 0; nt < 4; ++nt) {
      const int dc = wave * 64 + nt * 16 + lr;
      bv[nt] = *(const bf16x8*)(opb + ((size_t)dc) * 2048 + ks * 32 + lg * 8);
    }
#pragma unroll
    for (int nt = 0; nt < 4; ++nt)
#pragma unroll
      for (int mi = 0; mi < 2; ++mi)
        acc[mi][nt] = MFMA(av[mi], bv[nt], acc[mi][nt]);
  }
#pragma unroll
  for (int mi = 0; mi < 2; ++mi)
#pragma unroll
    for (int nt = 0; nt < 4; ++nt)
#pragma unroll
      for (int r = 0; r < 4; ++r) {
        const int row = wg * 32 + mi * 16 + lg * 4 + r;
        const int dc  = wave * 64 + nt * 16 + lr;
        out[(size_t)row * 256 + dc] = acc[mi][nt][r];
      }
}

// ---------------------------------------------------------------------------
extern "C" void kernel_launch(void* const* d_in, const int* in_sizes, int n_in,
                              void* d_out, int out_size, void* d_ws, size_t ws_size,
                              hipStream_t stream) {
  const float* x  = (const float*)d_in[0];
  const float* m  = (const float*)d_in[1];
  const float* qp = (const float*)d_in[2];
  const float* kp = (const float*)d_in[3];
  const float* vp = (const float*)d_in[4];
  const float* op = (const float*)d_in[5];
  float* out = (float*)d_out;

  unsigned short* xh  = (unsigned short*)d_ws;            // [8][1024][256]
  unsigned short* xl  = xh  + 2097152;
  unsigned short* mh  = xl  + 2097152;                    // [8][1024][256]
  unsigned short* ml  = mh  + 2097152;
  unsigned short* wh  = ml  + 2097152;                    // [8][256][256] (j major)
  unsigned short* wl  = wh  + 524288;
  unsigned short* opb = wl  + 524288;                     // [256][2048]
  __fp16*         vt  = (__fp16*)(opb + 524288);          // [8][256][1024] f16
  unsigned short* th  = (unsigned short*)(vt + 2097152);  // [8][8][1024][256]
  unsigned short* tl  = th  + 16777216;
  unsigned short* ob  = tl  + 16777216;                   // [8][1024][8][256]
  unsigned short* qph = ob  + 16777216;                   // [8][256][256]
  unsigned short* qpl = qph + 524288;
  unsigned short* kph = qpl + 524288;                     // [256][256]
  unsigned short* kpl = kph + 65536;
  unsigned short* vpt = kpl + 65536;                      // [256][256]

  k_prep<<<2048, 256, 0, stream>>>(x, m, op, qp, kp, vp, xh, xl, mh, ml, opb,
                                   qph, qpl, kph, kpl, vpt);
  k_w   <<<64,   256, 0, stream>>>(qph, qpl, kph, kpl, wh, wl);
  k_v   <<<256,  256, 0, stream>>>(vpt, mh, vt);
  k_t   <<<2048, 256, 0, stream>>>(xh, xl, wh, wl, th, tl);
  k_attn<<<1024, 256, 0, stream>>>(th, tl, mh, ml, vt, ob);
  k_out <<<256,  256, 0, stream>>>(ob, opb, out);
}

// Round 10
// 422.093 us; speedup vs baseline: 2.1875x; 1.2459x over previous
//
#include <hip/hip_runtime.h>
#include <math.h>

// Multi-query attention, MI355X gfx950.
// b=8, n=s=1024, d=k=v=256, h=8.
// Pre-softmax: bf16 hi/lo 3-pass MFMA (fp32-accurate logits, proven absmax 16).
// Post-softmax: f16 16x16x16 MFMA (lane-local P pack, no shuffles).
// k_attn: 4-wave WGs (64 q), 16-s blocks, K hi/lo + V(f16) double-buffered in
// LDS, flash online softmax, 1 vmcnt(0)+barrier per block. Round-10: batched
// ds_reads + V-reg preload + 256-VGPR budget (fix latency serialization).

typedef short bf16x8 __attribute__((ext_vector_type(8)));
typedef __fp16 f16x4 __attribute__((ext_vector_type(4)));
typedef float f32x4  __attribute__((ext_vector_type(4)));

#define MFMA(a, b, c)   __builtin_amdgcn_mfma_f32_16x16x32_bf16((a), (b), (c), 0, 0, 0)
#define MFMA16(a, b, c) __builtin_amdgcn_mfma_f32_16x16x16f16((a), (b), (c), 0, 0, 0)

typedef __attribute__((address_space(3))) unsigned int lds_u32_t;
typedef __attribute__((address_space(1))) const unsigned int glb_u32_t;

__device__ __forceinline__ unsigned short f32_bf16(float f) {
  unsigned u = __float_as_uint(f);
  u += 0x7FFFu + ((u >> 16) & 1u);   // RNE
  return (unsigned short)(u >> 16);
}
__device__ __forceinline__ float bf16_f32(unsigned short h) {
  return __uint_as_float(((unsigned)h) << 16);
}

// ---------------------------------------------------------------------------
// Prep: split x,m,qp,kp into bf16 hi/lo; output_proj -> bf16; vp -> vp^T bf16.
__global__ void k_prep(const float* __restrict__ x, const float* __restrict__ m,
                       const float* __restrict__ op, const float* __restrict__ qp,
                       const float* __restrict__ kp, const float* __restrict__ vp,
                       unsigned short* __restrict__ xh, unsigned short* __restrict__ xl,
                       unsigned short* __restrict__ mh, unsigned short* __restrict__ ml,
                       unsigned short* __restrict__ opb,
                       unsigned short* __restrict__ qph, unsigned short* __restrict__ qpl,
                       unsigned short* __restrict__ kph, unsigned short* __restrict__ kpl,
                       unsigned short* __restrict__ vpt) {
  const int tid = blockIdx.x * blockDim.x + threadIdx.x;
  const int stride = gridDim.x * blockDim.x;
  for (int i = tid; i < 2097152; i += stride) {
    float v = x[i];
    unsigned short h = f32_bf16(v);
    xh[i] = h; xl[i] = f32_bf16(v - bf16_f32(h));
    float w = m[i];
    unsigned short h2 = f32_bf16(w);
    mh[i] = h2; ml[i] = f32_bf16(w - bf16_f32(h2));
  }
  for (int i = tid; i < 524288; i += stride) {
    opb[i] = f32_bf16(op[i]);
    float q = qp[i];
    unsigned short h = f32_bf16(q);
    qph[i] = h; qpl[i] = f32_bf16(q - bf16_f32(h));
  }
  for (int i = tid; i < 65536; i += stride) {
    float k = kp[i];
    unsigned short h = f32_bf16(k);
    kph[i] = h; kpl[i] = f32_bf16(k - bf16_f32(h));
    const int vc = i >> 8, d = i & 255;
    vpt[i] = f32_bf16(vp[d * 256 + vc]);   // vpt[vc][d]
  }
}

// ---------------------------------------------------------------------------
// W[h][j][i] = sum_k Qp[h,i,k]*Kp[j,k]  (3-pass split MFMA, stored hi/lo).
__global__ __launch_bounds__(256) void k_w(
    const unsigned short* __restrict__ qph, const unsigned short* __restrict__ qpl,
    const unsigned short* __restrict__ kph, const unsigned short* __restrict__ kpl,
    unsigned short* __restrict__ wh, unsigned short* __restrict__ wl) {
  const int jt = blockIdx.x & 7;      // 64 WGs = 8h x 8jt
  const int h  = blockIdx.x >> 3;
  const int wave = threadIdx.x >> 6;
  const int lane = threadIdx.x & 63;
  const int lr = lane & 15, lg = lane >> 4;

  f32x4 acc[2][4];
  const f32x4 z = {0.f, 0.f, 0.f, 0.f};
#pragma unroll
  for (int mi = 0; mi < 2; ++mi)
#pragma unroll
    for (int nt = 0; nt < 4; ++nt) acc[mi][nt] = z;

  for (int ks = 0; ks < 8; ++ks) {
    bf16x8 ah[2], al[2], bh[4], bl[4];
#pragma unroll
    for (int mi = 0; mi < 2; ++mi) {
      const size_t aoff = ((size_t)(jt * 32 + mi * 16 + lr)) * 256 + ks * 32 + lg * 8;
      ah[mi] = *(const bf16x8*)(kph + aoff);
      al[mi] = *(const bf16x8*)(kpl + aoff);
    }
#pragma unroll
    for (int nt = 0; nt < 4; ++nt) {
      const size_t boff = ((size_t)(h * 256 + wave * 64 + nt * 16 + lr)) * 256 + ks * 32 + lg * 8;
      bh[nt] = *(const bf16x8*)(qph + boff);
      bl[nt] = *(const bf16x8*)(qpl + boff);
    }
#pragma unroll
    for (int nt = 0; nt < 4; ++nt)
#pragma unroll
      for (int mi = 0; mi < 2; ++mi) {
        acc[mi][nt] = MFMA(ah[mi], bh[nt], acc[mi][nt]);
        acc[mi][nt] = MFMA(ah[mi], bl[nt], acc[mi][nt]);
        acc[mi][nt] = MFMA(al[mi], bh[nt], acc[mi][nt]);
      }
  }
#pragma unroll
  for (int mi = 0; mi < 2; ++mi)
#pragma unroll
    for (int nt = 0; nt < 4; ++nt)
#pragma unroll
      for (int r = 0; r < 4; ++r) {
        const int j = jt * 32 + mi * 16 + lg * 4 + r;
        const int i = wave * 64 + nt * 16 + lr;
        const float v = acc[mi][nt][r];
        const size_t idx = ((size_t)(h * 256 + j)) * 256 + i;
        const unsigned short hi = f32_bf16(v);
        wh[idx] = hi;
        wl[idx] = f32_bf16(v - bf16_f32(hi));
      }
}

// ---------------------------------------------------------------------------
// vt[b][vc][s] = sum_d m[b,s,d]*vp[d,vc]  (1-pass bf16 MFMA, stored f16)
__global__ __launch_bounds__(256) void k_v(
    const unsigned short* __restrict__ vpt, const unsigned short* __restrict__ mh,
    __fp16* __restrict__ vt) {
  const int sc  = blockIdx.x & 3;     // 256 WGs = 8b x 8vct x 4sc
  const int vct = (blockIdx.x >> 2) & 7;
  const int b   = blockIdx.x >> 5;
  const int wave = threadIdx.x >> 6;
  const int lane = threadIdx.x & 63;
  const int lr = lane & 15, lg = lane >> 4;

  f32x4 acc[2][4];
  const f32x4 z = {0.f, 0.f, 0.f, 0.f};
#pragma unroll
  for (int mi = 0; mi < 2; ++mi)
#pragma unroll
    for (int nt = 0; nt < 4; ++nt) acc[mi][nt] = z;

  for (int ks = 0; ks < 8; ++ks) {
    bf16x8 av[2], bv[4];
#pragma unroll
    for (int mi = 0; mi < 2; ++mi)
      av[mi] = *(const bf16x8*)(vpt + ((size_t)(vct * 32 + mi * 16 + lr)) * 256 + ks * 32 + lg * 8);
#pragma unroll
    for (int nt = 0; nt < 4; ++nt)
      bv[nt] = *(const bf16x8*)(mh + ((size_t)(b * 1024 + sc * 256 + wave * 64 + nt * 16 + lr)) * 256 + ks * 32 + lg * 8);
#pragma unroll
    for (int nt = 0; nt < 4; ++nt)
#pragma unroll
      for (int mi = 0; mi < 2; ++mi)
        acc[mi][nt] = MFMA(av[mi], bv[nt], acc[mi][nt]);
  }
#pragma unroll
  for (int mi = 0; mi < 2; ++mi)
#pragma unroll
    for (int nt = 0; nt < 4; ++nt)
#pragma unroll
      for (int r = 0; r < 4; ++r) {
        const int vc = vct * 32 + mi * 16 + lg * 4 + r;
        const int s  = sc * 256 + wave * 64 + nt * 16 + lr;
        vt[((size_t)(b * 256 + vc)) * 1024 + s] = (__fp16)acc[mi][nt][r];
      }
}

// ---------------------------------------------------------------------------
// t[b][h][n][d'] = (x[b,n,:] @ W[h]) / 16, stored bf16 hi/lo (3-pass split MFMA)
__global__ __launch_bounds__(256) void k_t(
    const unsigned short* __restrict__ xh, const unsigned short* __restrict__ xl,
    const unsigned short* __restrict__ wh, const unsigned short* __restrict__ wl,
    unsigned short* __restrict__ th, unsigned short* __restrict__ tl) {
  const int wg = blockIdx.x;        // 2048 = b*h*(1024/32)
  const int mt = wg & 31;
  const int h  = (wg >> 5) & 7;
  const int b  = wg >> 8;
  const int wave = threadIdx.x >> 6;
  const int lane = threadIdx.x & 63;
  const int lr = lane & 15, lg = lane >> 4;

  f32x4 acc[2][4];
  const f32x4 z = {0.f, 0.f, 0.f, 0.f};
#pragma unroll
  for (int mi = 0; mi < 2; ++mi)
#pragma unroll
    for (int nt = 0; nt < 4; ++nt) acc[mi][nt] = z;

  for (int ks = 0; ks < 8; ++ks) {
    bf16x8 ahv[2], alv[2], bh4[4], bl4[4];
#pragma unroll
    for (int mi = 0; mi < 2; ++mi) {
      const size_t aoff = ((size_t)(b * 1024 + mt * 32 + mi * 16 + lr)) * 256 + ks * 32 + lg * 8;
      ahv[mi] = *(const bf16x8*)(xh + aoff);
      alv[mi] = *(const bf16x8*)(xl + aoff);
    }
#pragma unroll
    for (int nt = 0; nt < 4; ++nt) {
      const int dc = wave * 64 + nt * 16 + lr;
      const size_t boff = ((size_t)(h * 256 + dc)) * 256 + ks * 32 + lg * 8;
      bh4[nt] = *(const bf16x8*)(wh + boff);
      bl4[nt] = *(const bf16x8*)(wl + boff);
    }
#pragma unroll
    for (int nt = 0; nt < 4; ++nt)
#pragma unroll
      for (int mi = 0; mi < 2; ++mi) {
        acc[mi][nt] = MFMA(ahv[mi], bh4[nt], acc[mi][nt]);
        acc[mi][nt] = MFMA(ahv[mi], bl4[nt], acc[mi][nt]);
        acc[mi][nt] = MFMA(alv[mi], bh4[nt], acc[mi][nt]);
      }
  }
#pragma unroll
  for (int mi = 0; mi < 2; ++mi)
#pragma unroll
    for (int nt = 0; nt < 4; ++nt)
#pragma unroll
      for (int r = 0; r < 4; ++r) {
        const int row = mt * 32 + mi * 16 + lg * 4 + r;
        const int dc  = wave * 64 + nt * 16 + lr;
        const float v = acc[mi][nt][r] * 0.0625f;   // fold 1/sqrt(256)
        const size_t idx = ((size_t)((b * 8 + h) * 1024 + row)) * 256 + dc;
        const unsigned short hi = f32_bf16(v);
        th[idx] = hi;
        tl[idx] = f32_bf16(v - bf16_f32(hi));
      }
}

// ---------------------------------------------------------------------------
// Flash attention per (b, h, 64-q-row tile). 4 waves x 16 q-rows, 1024 WGs.
// 16-s blocks (64 iters). K hi/lo + V(f16) double-buffered (48 KB LDS).
// 256-VGPR budget: V-frags preloaded to regs, K-frags batched 8-at-a-time.
__global__ __launch_bounds__(256, 2) void k_attn(
    const unsigned short* __restrict__ th, const unsigned short* __restrict__ tl,
    const unsigned short* __restrict__ mh, const unsigned short* __restrict__ ml,
    const __fp16* __restrict__ vt, unsigned short* __restrict__ ob) {
  __shared__ __align__(16) unsigned short KH[2][4096];   // 16 s x 256 d (swizzled)
  __shared__ __align__(16) unsigned short KL[2][4096];
  __shared__ __align__(16) __fp16         VB[2][4096];   // 256 vc x 16 s (linear)

  const int wg0 = blockIdx.x;
  const int wg = (wg0 & 7) * 128 + (wg0 >> 3);  // XCD swizzle: b = XCD id
  const int qt = wg & 15;
  const int h  = (wg >> 4) & 7;
  const int b  = wg >> 7;
  const int wv = threadIdx.x >> 6;              // 0..3
  const int lane = threadIdx.x & 63;
  const int lr = lane & 15, lg = lane >> 4;
  const int start = ((qt << 3) + h) & 63;       // stagger block order per WG

  // Hoist t (B-operand for swapped QK^T): q = lr.
  const size_t trow = ((size_t)((b * 8 + h) * 1024 + qt * 64 + wv * 16 + lr)) * 256;
  bf16x8 Th[8], Tl[8];
#pragma unroll
  for (int d = 0; d < 8; ++d) {
    Th[d] = *(const bf16x8*)(th + trow + d * 32 + lg * 8);
    Tl[d] = *(const bf16x8*)(tl + trow + d * 32 + lg * 8);
  }

  const size_t mbase = (size_t)b * 1024 * 256;
  const size_t vbase = (size_t)b * 256 * 1024;

  // Stage K-block (16s x 256d, hi+lo). Linear LDS dest (wave-uniform base);
  // source pre-swizzled so LDS 16B-unit u holds global unit u ^ (s&7).
  auto stageK = [&](int lblk, int bi) {
    const int pb = (lblk + start) & 63;
#pragma unroll
    for (int i = 0; i < 2; ++i) {
      const int U = wv * 128 + i * 64 + lane;
      const int s_loc = U >> 5, u_phys = U & 31;
      const int u_log = u_phys ^ (s_loc & 7);
      const size_t soff = mbase + ((size_t)(pb * 16 + s_loc)) * 256 + u_log * 8;
      const int dsts = (wv * 128 + i * 64) * 8;      // shorts, wave-uniform
      __builtin_amdgcn_global_load_lds((glb_u32_t*)(mh + soff), (lds_u32_t*)&KH[bi][dsts], 16, 0, 0);
      __builtin_amdgcn_global_load_lds((glb_u32_t*)(ml + soff), (lds_u32_t*)&KL[bi][dsts], 16, 0, 0);
    }
  };
  // Stage V-block (256vc x 16s f16), rows 32B, linear.
  auto stageV = [&](int lblk, int bi) {
    const int pb = (lblk + start) & 63;
#pragma unroll
    for (int i = 0; i < 2; ++i) {
      const int U = wv * 128 + i * 64 + lane;
      const int vc = U >> 1, u = U & 1;
      const size_t soff = vbase + (size_t)vc * 1024 + pb * 16 + u * 8;
      const int dsth = (wv * 128 + i * 64) * 8;      // halfs, wave-uniform
      __builtin_amdgcn_global_load_lds((glb_u32_t*)(vt + soff), (lds_u32_t*)&VB[bi][dsth], 16, 0, 0);
    }
  };

  f32x4 Oacc[16];
  const f32x4 z = {0.f, 0.f, 0.f, 0.f};
#pragma unroll
  for (int i = 0; i < 16; ++i) Oacc[i] = z;
  float mrun = -1e30f, lrun = 0.0f;
  const float LOG2E = 1.44269504f;

  // ---- prologue: stage blocks 0 and 1 (6 loads per wave per stage)
  stageK(0, 0); stageV(0, 0);
  stageK(1, 1); stageV(1, 1);
  asm volatile("s_waitcnt vmcnt(6)" ::: "memory");   // stage(0) landed
  __builtin_amdgcn_s_barrier();

#pragma unroll 1
  for (int blk = 0; blk < 64; ++blk) {
    const int p = blk & 1;

    // ---- preload all 16 V-fragments (latency hides under QK^T + softmax)
    f16x4 Vf[16];
#pragma unroll
    for (int nt = 0; nt < 16; ++nt)
      Vf[nt] = *(const f16x4*)&VB[p][(nt * 16 + lr) * 16 + lg * 4];

    // ---- QK^T(blk): S^T tile (s = lg*4+r, q = lr); 2 half-passes of 8
    // batched ds_read_b128 -> 12 MFMA (3 independent chains).
    f32x4 Sa = z, Sb = z, Sc = z;
#pragma unroll
    for (int half = 0; half < 2; ++half) {
      bf16x8 ah[4], al[4];
#pragma unroll
      for (int dd = 0; dd < 4; ++dd) {
        const int d = half * 4 + dd;
        const int u0 = ((d * 4 + lg) ^ (lr & 7)) * 8;
        ah[dd] = *(const bf16x8*)&KH[p][lr * 256 + u0];
        al[dd] = *(const bf16x8*)&KL[p][lr * 256 + u0];
      }
#pragma unroll
      for (int dd = 0; dd < 4; ++dd) {
        const int d = half * 4 + dd;
        Sa = MFMA(ah[dd], Th[d], Sa);
        Sb = MFMA(ah[dd], Tl[d], Sb);
        Sc = MFMA(al[dd], Th[d], Sc);
      }
    }
    const f32x4 S = (Sa + Sb) + Sc;

    // ---- online softmax (q = lr domain)
    float bm = fmaxf(fmaxf(S[0], S[1]), fmaxf(S[2], S[3]));
    bm = fmaxf(bm, __shfl_xor(bm, 16));
    bm = fmaxf(bm, __shfl_xor(bm, 32));
    if (!__all(bm - mrun <= 8.0f)) {            // defer-max: THR = 8 nats
      const float mnew = fmaxf(mrun, bm);
      const float sc = exp2f((mrun - mnew) * LOG2E);
      const float s0 = __shfl(sc, lg * 4 + 0);
      const float s1 = __shfl(sc, lg * 4 + 1);
      const float s2 = __shfl(sc, lg * 4 + 2);
      const float s3 = __shfl(sc, lg * 4 + 3);
#pragma unroll
      for (int nt = 0; nt < 16; ++nt) {
        Oacc[nt][0] *= s0; Oacc[nt][1] *= s1; Oacc[nt][2] *= s2; Oacc[nt][3] *= s3;
      }
      lrun *= sc;
      mrun = mnew;
    }
    float pr[4];
#pragma unroll
    for (int r = 0; r < 4; ++r) pr[r] = exp2f((S[r] - mrun) * LOG2E);
    float rs = (pr[0] + pr[1]) + (pr[2] + pr[3]);
    rs += __shfl_xor(rs, 16);
    rs += __shfl_xor(rs, 32);
    lrun += rs;

    // ---- pack P: lane-local! A-frag[m=lr][k=lg*4+j] == this lane's pr[j]
    const auto c01 = __builtin_amdgcn_cvt_pkrtz(pr[0], pr[1]);   // __fp16 x2
    const auto c23 = __builtin_amdgcn_cvt_pkrtz(pr[2], pr[3]);
    f16x4 pa;
    pa[0] = c01[0]; pa[1] = c01[1]; pa[2] = c23[0]; pa[3] = c23[1];

    // ---- PV(blk): B-frags already in registers
#pragma unroll
    for (int nt = 0; nt < 16; ++nt)
      Oacc[nt] = MFMA16(pa, Vf[nt], Oacc[nt]);

    // ---- pipeline: stage(blk+1) drained; all waves past reads of buffers p
    if (blk < 63) {
      asm volatile("s_waitcnt vmcnt(0)" ::: "memory");
      __builtin_amdgcn_s_barrier();
      if (blk < 62) { stageK(blk + 2, p); stageV(blk + 2, p); }
    }
  }

  // ---- epilogue
  const float inv = 1.0f / lrun;
  const float i0 = __shfl(inv, lg * 4 + 0);
  const float i1 = __shfl(inv, lg * 4 + 1);
  const float i2 = __shfl(inv, lg * 4 + 2);
  const float i3 = __shfl(inv, lg * 4 + 3);
  const int qg = qt * 64 + wv * 16 + lg * 4;
  const size_t obase = ((size_t)(b * 1024 + qg) * 8 + h) * 256 + lr;
#pragma unroll
  for (int nt = 0; nt < 16; ++nt) {
    ob[obase + 0 * 2048 + nt * 16] = f32_bf16(Oacc[nt][0] * i0);
    ob[obase + 1 * 2048 + nt * 16] = f32_bf16(Oacc[nt][1] * i1);
    ob[obase + 2 * 2048 + nt * 16] = f32_bf16(Oacc[nt][2] * i2);
    ob[obase + 3 * 2048 + nt * 16] = f32_bf16(Oacc[nt][3] * i3);
  }
}

// ---------------------------------------------------------------------------
// out[bn][d] = o[bn][hv] @ OpB[d][hv]^T  (M=8192, K=2048, N=256)
__global__ __launch_bounds__(256) void k_out(
    const unsigned short* __restrict__ ob, const unsigned short* __restrict__ opb,
    float* __restrict__ out) {
  const int wg = blockIdx.x;        // 256 = 8192/32
  const int wave = threadIdx.x >> 6;
  const int lane = threadIdx.x & 63;
  const int lr = lane & 15, lg = lane >> 4;

  f32x4 acc[2][4];
  const f32x4 z = {0.f, 0.f, 0.f, 0.f};
#pragma unroll
  for (int mi = 0; mi < 2; ++mi)
#pragma unroll
    for (int nt = 0; nt < 4; ++nt) acc[mi][nt] = z;

  for (int ks = 0; ks < 64; ++ks) {
    bf16x8 av[2], bv[4];
#pragma unroll
    for (int mi = 0; mi < 2; ++mi) {
      const size_t aoff = ((size_t)(wg * 32 + mi * 16 + lr)) * 2048 + ks * 32 + lg * 8;
      av[mi] = *(const bf16x8*)(ob + aoff);
    }
#pragma unroll
    for (int nt = 0; nt < 4; ++nt) {
      const int dc = wave * 64 + nt * 16 + lr;
      bv[nt] = *(const bf16x8*)(opb + ((size_t)dc) * 2048 + ks * 32 + lg * 8);
    }
#pragma unroll
    for (int nt = 0; nt < 4; ++nt)
#pragma unroll
      for (int mi = 0; mi < 2; ++mi)
        acc[mi][nt] = MFMA(av[mi], bv[nt], acc[mi][nt]);
  }
#pragma unroll
  for (int mi = 0; mi < 2; ++mi)
#pragma unroll
    for (int nt = 0; nt < 4; ++nt)
#pragma unroll
      for (int r = 0; r < 4; ++r) {
        const int row = wg * 32 + mi * 16 + lg * 4 + r;
        const int dc  = wave * 64 + nt * 16 + lr;
        out[(size_t)row * 256 + dc] = acc[mi][nt][r];
      }
}

// ---------------------------------------------------------------------------
extern "C" void kernel_launch(void* const* d_in, const int* in_sizes, int n_in,
                              void* d_out, int out_size, void* d_ws, size_t ws_size,
                              hipStream_t stream) {
  const float* x  = (const float*)d_in[0];
  const float* m  = (const float*)d_in[1];
  const float* qp = (const float*)d_in[2];
  const float* kp = (const float*)d_in[3];
  const float* vp = (const float*)d_in[4];
  const float* op = (const float*)d_in[5];
  float* out = (float*)d_out;

  unsigned short* xh  = (unsigned short*)d_ws;            // [8][1024][256]
  unsigned short* xl  = xh  + 2097152;
  unsigned short* mh  = xl  + 2097152;                    // [8][1024][256]
  unsigned short* ml  = mh  + 2097152;
  unsigned short* wh  = ml  + 2097152;                    // [8][256][256] (j major)
  unsigned short* wl  = wh  + 524288;
  unsigned short* opb = wl  + 524288;                     // [256][2048]
  __fp16*         vt  = (__fp16*)(opb + 524288);          // [8][256][1024] f16
  unsigned short* th  = (unsigned short*)(vt + 2097152);  // [8][8][1024][256]
  unsigned short* tl  = th  + 16777216;
  unsigned short* ob  = tl  + 16777216;                   // [8][1024][8][256]
  unsigned short* qph = ob  + 16777216;                   // [8][256][256]
  unsigned short* qpl = qph + 524288;
  unsigned short* kph = qpl + 524288;                     // [256][256]
  unsigned short* kpl = kph + 65536;
  unsigned short* vpt = kpl + 65536;                      // [256][256]

  k_prep<<<2048, 256, 0, stream>>>(x, m, op, qp, kp, vp, xh, xl, mh, ml, opb,
                                   qph, qpl, kph, kpl, vpt);
  k_w   <<<64,   256, 0, stream>>>(qph, qpl, kph, kpl, wh, wl);
  k_v   <<<256,  256, 0, stream>>>(vpt, mh, vt);
  k_t   <<<2048, 256, 0, stream>>>(xh, xl, wh, wl, th, tl);
  k_attn<<<1024, 256, 0, stream>>>(th, tl, mh, ml, vt, ob);
  k_out <<<256,  256, 0, stream>>>(ob, opb, out);
}